// Round 2
// baseline (248.849 us; speedup 1.0000x reference)
//
#include <hip/hip_runtime.h>

// PatchShuffle: B=64 batches, 16x64 grid of patches, stripe width 48, C=768.
// Outputs (concatenated float32 in d_out):
//   visible      : (256, 64, 768)  = 12,582,912 elems
//   fwd          : (1024, 64)      =     65,536 elems (int values as float)
//   bwd          : (1024, 64)      =     65,536 elems
//   stripe_bounds: (2, 64)         =        128 elems
// total out_size = 12,714,112

#define NROWS     16
#define NCOLS     64
#define NB        64
#define NC        768
#define SW        48
#define NVIS_COLS (NCOLS - SW)          // 16
#define MIN_VIS   (NROWS * NVIS_COLS)   // 256
#define VIS_ELEMS (MIN_VIS * NB * NC)   // 12,582,912
#define TBC       (NROWS * NCOLS)       // 1024
#define C4        (NC / 4)              // 192 float4 per row
#define NV4       (VIS_ELEMS / 4)       // 3,145,728 float4 work items
#define NFWD      (TBC * NB)            // 65,536
#define NTOT_IDX  (2 * NFWD + 2 * NB)   // 131,200 scalar work items

// perm[j] for start s (s in [0,16]): non-stripe cols ascending, then stripe cols.
__device__ __forceinline__ int permcol(int s, int j) {
    return (j < NVIS_COLS) ? ((j < s) ? j : j + SW) : (s + j - NVIS_COLS);
}
// inverse: column c -> position j  (valid for s in [0,16], SW=48)
__device__ __forceinline__ int invcol(int s, int c) {
    return (c < s) ? c : ((c >= s + SW) ? (c - SW) : (c - s + NVIS_COLS));
}

__global__ __launch_bounds__(256) void patchshuffle_fused_kernel(
        const float4* __restrict__ patches,   // (1024, 64, 192) float4
        const int*    __restrict__ start_cols,
        float*        __restrict__ out) {     // full output buffer
    float4* __restrict__ vis_out = (float4*)out;          // (256,64,192) float4
    float*  __restrict__ idx_out = out + VIS_ELEMS;       // fwd|bwd|bounds

    const int total  = NV4 + NTOT_IDX;
    const int stride = gridDim.x * blockDim.x;
    for (int g = blockIdx.x * blockDim.x + threadIdx.x; g < total; g += stride) {
        if (g < NV4) {
            // visible gather, 16B per item, coalesced on both sides
            int ib = g / C4;                      // 0..16383  (i*64 + b)
            int c4 = g - ib * C4;
            int b  = ib & (NB - 1);
            int i  = ib >> 6;                     // 0..255
            int s  = start_cols[b];
            int col = permcol(s, i & (NCOLS - 1));
            int src_t = (i & ~(NCOLS - 1)) + col; // (i/64)*64 + col
            vis_out[ib * C4 + c4] = patches[(src_t * NB + b) * C4 + c4];
        } else {
            int g0 = g - NV4;
            float v;
            if (g0 < NFWD) {                      // fwd[t][b] = (t/64)*64 + perm[t%64]
                int t = g0 >> 6, b = g0 & (NB - 1);
                int s = start_cols[b];
                v = (float)((t & ~(NCOLS - 1)) + permcol(s, t & (NCOLS - 1)));
            } else if (g0 < 2 * NFWD) {           // bwd[p][b] = (p/64)*64 + inv[p%64]
                int g2 = g0 - NFWD;
                int p = g2 >> 6, b = g2 & (NB - 1);
                int s = start_cols[b];
                v = (float)((p & ~(NCOLS - 1)) + invcol(s, p & (NCOLS - 1)));
            } else {                              // stripe_bounds: 64 starts, 64 ends
                int g3 = g0 - 2 * NFWD;
                int b = g3 & (NB - 1);
                int s = start_cols[b];
                v = (float)((g3 < NB) ? s : s + SW);
            }
            idx_out[g0] = v;
        }
    }
}

extern "C" void kernel_launch(void* const* d_in, const int* in_sizes, int n_in,
                              void* d_out, int out_size, void* d_ws, size_t ws_size,
                              hipStream_t stream) {
    const float4* patches    = (const float4*)d_in[0];
    const int*    start_cols = (const int*)d_in[1];
    float* out = (float*)d_out;

    // one fused launch: 3,145,728 float4 gathers + 131,200 scalar index writes
    patchshuffle_fused_kernel<<<2048, 256, 0, stream>>>(patches, start_cols, out);
}